// Round 8
// baseline (446.211 us; speedup 1.0000x reference)
//
#include <hip/hip_runtime.h>
#include <hip/hip_bf16.h>

#define NPTS 8192
#define NB   4
#define NQI  8                     // (batch, side) pairs
#define BLK  256
#define G    64                    // grid cells per axis
#define G2   (G * G)               // 4096 cells
#define CMAX 8.0f                  // domain [-8,8] (N(0,sqrt2) max ~6)
#define CELLW 0.25f
#define INVCW 4.0f
#define THR  3.33f
#define RMAX 8                     // rings 0..8 cover d < sqrt(3.33)=1.825
#define NCHUNK 32                  // worst-case 8192 queries / 256

// workspace layout (all words plain-stored every call; no init node):
//   byte 0      : part[NQI][NCHUNK][2] f32 (2 KB)
//   byte 4096   : off[NQI][G2+1] u32 (131104 B)
//   byte 135200 : sorted[NQI][NPTS] float4 (1 MB) encoded (2x,2y,2z,-|p|^2)
#define OFF_OFF  4096
#define OFF_SORT 135200

__device__ __forceinline__ void load_pt(int side, int g,
    const float* __restrict__ Ps, const float* __restrict__ Pd,
    const float* __restrict__ F,  const int* __restrict__ Ms,
    const int* __restrict__ Md,
    float& x, float& y, float& z, bool& v)
{
    if (side == 0) {               // warped src
        x = Ps[3*g+0] + F[3*g+0];
        y = Ps[3*g+1] + F[3*g+1];
        z = Ps[3*g+2] + F[3*g+2];
        v = Ms[g] > 0;
    } else {                       // dst
        x = Pd[3*g+0]; y = Pd[3*g+1]; z = Pd[3*g+2];
        v = Md[g] > 0;
    }
}

__device__ __forceinline__ int cell_of(float x) {
    int c = (int)((x + CMAX) * INVCW);
    if (c < 0) c = 0;
    if (c > G - 1) c = G - 1;
    return c;
}

// ---------------------------------------------------------------------------
// PREP: one block per qi=(b,side). Pass1: LDS histogram of valid points by
// (cy,cx). Scan in LDS (256 thr x 16 entries), write exclusive offsets to
// global. Pass2: scatter encoded points to cell-sorted order via LDS cursors.
// ---------------------------------------------------------------------------
__global__ __launch_bounds__(BLK) void prep_kernel(
    const float* __restrict__ Ps, const float* __restrict__ Pd,
    const float* __restrict__ F,  const int* __restrict__ Ms,
    const int* __restrict__ Md,   unsigned* __restrict__ off_g,
    float4* __restrict__ sorted)
{
    const int qi = blockIdx.x;
    const int b = qi >> 1, side = qi & 1;
    const int tid = threadIdx.x, lane = tid & 63, w = tid >> 6;

    __shared__ unsigned hist[G2];          // 16 KB; becomes cursors after scan
    __shared__ unsigned wtot[4];

    for (int i = tid; i < G2; i += BLK) hist[i] = 0;
    __syncthreads();

    // pass 1: histogram
    for (int i = tid; i < NPTS; i += BLK) {
        float x, y, z; bool v;
        load_pt(side, b * NPTS + i, Ps, Pd, F, Ms, Md, x, y, z, v);
        if (v) atomicAdd(&hist[cell_of(y) * G + cell_of(x)], 1u);
    }
    __syncthreads();

    // scan: each thread owns 16 contiguous entries
    const int base = tid * 16;
    unsigned ssum = 0;
#pragma unroll
    for (int j = 0; j < 16; ++j) ssum += hist[base + j];
    unsigned incl = ssum;
#pragma unroll
    for (int o = 1; o < 64; o <<= 1) {
        unsigned t = __shfl_up(incl, o);
        if (lane >= o) incl += t;
    }
    if (lane == 63) wtot[w] = incl;
    __syncthreads();
    unsigned wex = 0;
#pragma unroll
    for (int i = 0; i < 4; ++i) if (i < w) wex += wtot[i];
    unsigned run = wex + incl - ssum;      // exclusive prefix for this chunk
    unsigned* og = off_g + (size_t)qi * (G2 + 1);
#pragma unroll
    for (int j = 0; j < 16; ++j) {
        const unsigned e = hist[base + j];
        og[base + j] = run;
        hist[base + j] = run;              // cursor
        run += e;
    }
    if (tid == BLK - 1) og[G2] = run;      // nq (total valid)
    __syncthreads();

    // pass 2: scatter encoded points
    for (int i = tid; i < NPTS; i += BLK) {
        float x, y, z; bool v;
        load_pt(side, b * NPTS + i, Ps, Pd, F, Ms, Md, x, y, z, v);
        if (v) {
            const int cell = cell_of(y) * G + cell_of(x);
            const unsigned pos = atomicAdd(&hist[cell], 1u);
            sorted[(size_t)qi * NPTS + pos] =
                make_float4(2.f * x, 2.f * y, 2.f * z,
                            -fmaf(x, x, fmaf(y, y, z * z)));
        }
    }
}

// ---------------------------------------------------------------------------
// NN: block = (chunk, qi). One sorted query per thread (cell-coherent waves).
// Concentric-ring walk over search side's cells with exact lower-bound stop:
// process ring r iff ((r-1)*CELLW)^2 < min(best_d2, THR). Candidates within a
// row-run of cells are contiguous in the sorted array.
// ---------------------------------------------------------------------------
__global__ __launch_bounds__(BLK) void nn_kernel(
    const unsigned* __restrict__ off_g, const float4* __restrict__ sorted,
    float* __restrict__ part)
{
    const int chunk = blockIdx.x, qi = blockIdx.y;
    const int si = qi ^ 1;                 // search side: other side, same b
    const int tid = threadIdx.x, lane = tid & 63, w = tid >> 6;

    __shared__ unsigned soff[G2 + 1];      // search side offsets
    __shared__ float red[8];

    const unsigned nq = off_g[(size_t)qi * (G2 + 1) + G2];
    float s = 0.f, c = 0.f;

    if ((unsigned)(chunk * BLK) < nq) {    // block-uniform
        const unsigned* offs = off_g + (size_t)si * (G2 + 1);
        for (int i = tid; i < G2 + 1; i += BLK) soff[i] = offs[i];
        __syncthreads();

        const int idx = chunk * BLK + tid;
        const bool isq = idx < (int)nq;
        float qx = 0.f, qy = 0.f, qz = 0.f, qw = 0.f;
        int cx = 0, cy = 0;
        if (isq) {
            const float4 p = sorted[(size_t)qi * NPTS + idx];
            qx = 0.5f * p.x; qy = 0.5f * p.y; qz = 0.5f * p.z;
            qw = -p.w;                     // |q|^2
            cx = cell_of(qx); cy = cell_of(qy);
        }
        const float4* sarr = sorted + (size_t)si * NPTS;
        float bestT = -1e30f;
        bool active = isq;

        for (int r = 0; r <= RMAX; ++r) {
            if (active) {
                const float lbs = (r > 0) ? (float)(r - 1) * CELLW : 0.f;
                const float lb = lbs * lbs;
                if (lb >= fminf(qw - bestT, THR)) active = false;
            }
            if (__all(!active)) break;
            if (active) {
                for (int dy = -r; dy <= r; ++dy) {
                    const int cy2 = cy + dy;
                    if ((unsigned)cy2 >= (unsigned)G) continue;
                    const int rowb = cy2 * G;
                    if (dy == -r || dy == r) {     // full row run
                        int a = cx - r; if (a < 0) a = 0;
                        int e = cx + r; if (e > G - 1) e = G - 1;
                        const unsigned j0 = soff[rowb + a];
                        const unsigned j1 = soff[rowb + e + 1];
                        for (unsigned j = j0; j < j1; ++j) {
                            const float4 sp = sarr[j];
                            float t = fmaf(qx, sp.x, sp.w);
                            t = fmaf(qy, sp.y, t);
                            t = fmaf(qz, sp.z, t);
                            bestT = fmaxf(bestT, t);
                        }
                    } else {                        // two edge cells
                        const int a = cx - r;
                        if (a >= 0) {
                            const unsigned j0 = soff[rowb + a];
                            const unsigned j1 = soff[rowb + a + 1];
                            for (unsigned j = j0; j < j1; ++j) {
                                const float4 sp = sarr[j];
                                float t = fmaf(qx, sp.x, sp.w);
                                t = fmaf(qy, sp.y, t);
                                t = fmaf(qz, sp.z, t);
                                bestT = fmaxf(bestT, t);
                            }
                        }
                        const int e = cx + r;
                        if (e <= G - 1) {
                            const unsigned j0 = soff[rowb + e];
                            const unsigned j1 = soff[rowb + e + 1];
                            for (unsigned j = j0; j < j1; ++j) {
                                const float4 sp = sarr[j];
                                float t = fmaf(qx, sp.x, sp.w);
                                t = fmaf(qy, sp.y, t);
                                t = fmaf(qz, sp.z, t);
                                bestT = fmaxf(bestT, t);
                            }
                        }
                    }
                }
            }
        }
        if (isq) {
            const float dd = fmaxf(qw - bestT, 0.f);
            if (dd < THR) { s = dd; c = 1.f; }
        }
    }

    // block reduce (all threads reach here; skipped blocks contribute 0)
#pragma unroll
    for (int off = 32; off; off >>= 1) {
        s += __shfl_down(s, off);
        c += __shfl_down(c, off);
    }
    if (lane == 0) { red[w] = s; red[4 + w] = c; }
    __syncthreads();
    if (tid == 0) {
        part[(qi * NCHUNK + chunk) * 2 + 0] = red[0] + red[1] + red[2] + red[3];
        part[(qi * NCHUNK + chunk) * 2 + 1] = red[4] + red[5] + red[6] + red[7];
    }
}

// ---------------------------------------------------------------------------
// F: sum per-qi partials, mean = s/c, out = sum of 8 means. 1 block, 64 thr.
// ---------------------------------------------------------------------------
__global__ void out_kernel(const float* __restrict__ part,
                           float* __restrict__ out)
{
    const int tid = threadIdx.x;
    float a = 0.f;
    if (tid < NQI) {
        float s = 0.f, c = 0.f;
        for (int k = 0; k < NCHUNK; ++k) {
            s += part[(tid * NCHUNK + k) * 2 + 0];
            c += part[(tid * NCHUNK + k) * 2 + 1];
        }
        a = s / c;
    }
#pragma unroll
    for (int off = 4; off; off >>= 1) a += __shfl_down(a, off);
    if (tid == 0) out[0] = a;
}

extern "C" void kernel_launch(void* const* d_in, const int* in_sizes, int n_in,
                              void* d_out, int out_size, void* d_ws, size_t ws_size,
                              hipStream_t stream)
{
    const float* Ps = (const float*)d_in[0];   // points_src  [B,N,3]
    const float* Pd = (const float*)d_in[1];   // points_dst  [B,N,3]
    const float* F  = (const float*)d_in[2];   // flows_pred  [B,N,3]
    // d_in[3] = flows_gt (unused by reference)
    const int* Ms = (const int*)d_in[4];       // masks_src [B,N]
    const int* Md = (const int*)d_in[5];       // masks_dst [B,N]
    float* out = (float*)d_out;

    float* part = (float*)d_ws;
    unsigned* off_g = (unsigned*)((char*)d_ws + OFF_OFF);
    float4* sorted = (float4*)((char*)d_ws + OFF_SORT);

    prep_kernel<<<dim3(NQI), BLK, 0, stream>>>(Ps, Pd, F, Ms, Md, off_g, sorted);

    nn_kernel<<<dim3(NCHUNK, NQI), BLK, 0, stream>>>(off_g, sorted, part);

    out_kernel<<<1, 64, 0, stream>>>(part, out);
}

// Round 10
// 33.391 us; speedup vs baseline: 13.3630x; 13.3630x over previous
//
#include <hip/hip_runtime.h>
#include <hip/hip_bf16.h>

#define NPTS 8192
#define NB   4
#define BLK  256
#define RAWC 2048                 // raw queries per chunk -> dense ~1024, KMAX=4
#define NQC  (NPTS / RAWC)        // 4 chunks
#define NSL  16                   // search slices
#define SRAW (NPTS / NSL)         // 512 raw search points per slice
#define NQI  (2 * NB)             // 8 (batch,dir) pairs
#define NGRP (NQI * NQC)          // 32 groups
#define THR  3.33f

// workspace:
//   ctl[0..511] words: ticket1[qi] @ qi*32 (zeroed by knn blk0 each call),
//                      ticket2 @ 256, meanv[8] f32 @ 288.
//   ctl[1056..1087]: psum[32] f32 ; ctl[1088..1119]: pcnt[32] f32
//                      (plain-stored by final before read).
//   byte 8192: part[NGRP][NSL][RAWC] f32 = 4 MB (knn stores, final reads —
//              cross-kernel handoff only).
#define OFF_PART 8192

__device__ __forceinline__ void load_pt(int side, int g,
    const float* __restrict__ Ps, const float* __restrict__ Pd,
    const float* __restrict__ F,  const int* __restrict__ Ms,
    const int* __restrict__ Md,
    float& x, float& y, float& z, bool& v)
{
    if (side == 0) {               // warped src
        x = Ps[3*g+0] + F[3*g+0];
        y = Ps[3*g+1] + F[3*g+1];
        z = Ps[3*g+2] + F[3*g+2];
        v = Ms[g] > 0;
    } else {                       // dst
        x = Pd[3*g+0]; y = Pd[3*g+1]; z = Pd[3*g+2];
        v = Md[g] > 0;
    }
}

// dense inner loop: KMAX queries/thread vs sd staged search pts (broadcast)
template<int KMAX>
__device__ __forceinline__ void inner_loop(const float4* __restrict__ sp, int sd,
                                           const float4* __restrict__ qb, int nd,
                                           float* __restrict__ pb, int tid)
{
    float qx[KMAX], qy[KMAX], qz[KMAX], bt[KMAX];
#pragma unroll
    for (int k = 0; k < KMAX; ++k) {
        const int q = k * BLK + tid;
        const float4 p = qb[q < nd ? q : 0];
        qx[k] = p.x; qy[k] = p.y; qz[k] = p.z;
        bt[k] = -1e30f;
    }
#pragma unroll 4
    for (int j = 0; j < sd; ++j) {
        const float4 s = sp[j];            // wave-uniform -> LDS broadcast
#pragma unroll
        for (int k = 0; k < KMAX; ++k) {
            float t = fmaf(qx[k], s.x, s.w);
            t = fmaf(qy[k], s.y, t);
            t = fmaf(qz[k], s.z, t);
            bt[k] = fmaxf(bt[k], t);
        }
    }
#pragma unroll
    for (int k = 0; k < KMAX; ++k) {
        const int q = k * BLK + tid;
        if (q < nd) pb[q] = bt[k];         // coalesced plain store
    }
}

// ---------------------------------------------------------------------------
// knn: block = (chunk qc, slice sl, dir, b). Compact 2048 raw queries (dense
// ~1024 -> KMAX=4) + 512 raw search pts into LDS; dense max-t loop; per-slice
// maxima stored to part. Block (0,0,0) zeroes the 512 ctl words (consumed by
// final across the kernel boundary -> safe, R6-proven).
// ---------------------------------------------------------------------------
__global__ __launch_bounds__(BLK) void knn_kernel(
    const float* __restrict__ Ps, const float* __restrict__ Pd,
    const float* __restrict__ F,  const int* __restrict__ Ms,
    const int* __restrict__ Md,   float* __restrict__ part,
    unsigned* __restrict__ ctl)
{
    const int b = blockIdx.z, dir = blockIdx.y;
    const int qc = blockIdx.x / NSL, sl = blockIdx.x % NSL;
    const int qi = b * 2 + dir, grp = qi * NQC + qc;
    const int tid = threadIdx.x, lane = tid & 63, w = tid >> 6;

    if (blockIdx.x == 0 && dir == 0 && b == 0)
        for (int i = tid; i < 512; i += BLK) ctl[i] = 0;

    __shared__ float4 qb[RAWC];            // 32 KB dense queries (x,y,z,|q|^2)
    __shared__ float4 sp[SRAW];            // 8 KB dense search (2x,2y,2z,-|s|^2)
    __shared__ int wcq[4], wcs[4], cnt_s[2];

    // raw loads: 8 query + 2 search points per thread
    float qx[8], qy[8], qz[8]; bool qv[8];
#pragma unroll
    for (int r = 0; r < 8; ++r) {
        const int g = b * NPTS + qc * RAWC + r * BLK + tid;
        load_pt(dir, g, Ps, Pd, F, Ms, Md, qx[r], qy[r], qz[r], qv[r]);
    }
    float sx[2], sy[2], sz[2]; bool sv[2];
#pragma unroll
    for (int r = 0; r < 2; ++r) {
        const int g = b * NPTS + sl * SRAW + r * BLK + tid;
        load_pt(1 - dir, g, Ps, Pd, F, Ms, Md, sx[r], sy[r], sz[r], sv[r]);
    }

    // block-wide stable compaction (wave shfl-scan + cross-wave offsets)
    int cq = 0, cs = 0;
#pragma unroll
    for (int r = 0; r < 8; ++r) cq += qv[r];
#pragma unroll
    for (int r = 0; r < 2; ++r) cs += sv[r];
    int pq = cq, ps = cs;
#pragma unroll
    for (int o = 1; o < 64; o <<= 1) {
        int t1 = __shfl_up(pq, o), t2 = __shfl_up(ps, o);
        if (lane >= o) { pq += t1; ps += t2; }
    }
    if (lane == 63) { wcq[w] = pq; wcs[w] = ps; }
    __syncthreads();
    int bq = 0, bs = 0;
#pragma unroll
    for (int i = 0; i < 4; ++i) if (i < w) { bq += wcq[i]; bs += wcs[i]; }
    int oq = bq + pq - cq, os = bs + ps - cs;
#pragma unroll
    for (int r = 0; r < 8; ++r)
        if (qv[r]) {
            qb[oq] = make_float4(qx[r], qy[r], qz[r],
                     fmaf(qx[r], qx[r], fmaf(qy[r], qy[r], qz[r] * qz[r])));
            ++oq;
        }
#pragma unroll
    for (int r = 0; r < 2; ++r)
        if (sv[r]) {
            sp[os] = make_float4(2.f * sx[r], 2.f * sy[r], 2.f * sz[r],
                     -fmaf(sx[r], sx[r], fmaf(sy[r], sy[r], sz[r] * sz[r])));
            ++os;
        }
    if (tid == BLK - 1) { cnt_s[0] = bq + pq; cnt_s[1] = bs + ps; }
    __syncthreads();
    const int nd = cnt_s[0], sd = cnt_s[1];

    float* pb = part + ((size_t)grp * NSL + sl) * RAWC;
    switch ((nd + BLK - 1) >> 8) {         // block-uniform KMAX dispatch
        case 1: inner_loop<1>(sp, sd, qb, nd, pb, tid); break;
        case 2: inner_loop<2>(sp, sd, qb, nd, pb, tid); break;
        case 3: inner_loop<3>(sp, sd, qb, nd, pb, tid); break;
        case 4: inner_loop<4>(sp, sd, qb, nd, pb, tid); break;
        case 5: inner_loop<5>(sp, sd, qb, nd, pb, tid); break;
        case 6: inner_loop<6>(sp, sd, qb, nd, pb, tid); break;
        case 7: inner_loop<7>(sp, sd, qb, nd, pb, tid); break;
        case 8: inner_loop<8>(sp, sd, qb, nd, pb, tid); break;
        default: break;                    // nd == 0
    }
}

// ---------------------------------------------------------------------------
// final: block = (qc, dir, b) = 32 blocks. Re-compact own chunk (identical
// dense order), max over 16 slice planes of part (cross-kernel), threshold,
// block-reduce, then shallow 2-level ticket (depth 4, then 8) -> out[0].
// Intra-kernel handoff limited to psum/pcnt/meanv scalars (R6-proven).
// ---------------------------------------------------------------------------
__global__ __launch_bounds__(BLK) void final_kernel(
    const float* __restrict__ Ps, const float* __restrict__ Pd,
    const float* __restrict__ F,  const int* __restrict__ Ms,
    const int* __restrict__ Md,   const float* __restrict__ part,
    unsigned* __restrict__ ctl,   float* __restrict__ out)
{
    const int b = blockIdx.z, dir = blockIdx.y, qc = blockIdx.x;
    const int qi = b * 2 + dir, grp = qi * NQC + qc;
    const int tid = threadIdx.x, lane = tid & 63, w = tid >> 6;

    __shared__ float q2b[RAWC];            // 8 KB dense |q|^2
    __shared__ int wcq[4], nd_s;
    __shared__ float red[8];

    float qx[8], qy[8], qz[8]; bool qv[8];
#pragma unroll
    for (int r = 0; r < 8; ++r) {
        const int g = b * NPTS + qc * RAWC + r * BLK + tid;
        load_pt(dir, g, Ps, Pd, F, Ms, Md, qx[r], qy[r], qz[r], qv[r]);
    }
    int cq = 0;
#pragma unroll
    for (int r = 0; r < 8; ++r) cq += qv[r];
    int pq = cq;
#pragma unroll
    for (int o = 1; o < 64; o <<= 1) {
        int t1 = __shfl_up(pq, o);
        if (lane >= o) pq += t1;
    }
    if (lane == 63) wcq[w] = pq;
    __syncthreads();
    int bq = 0;
#pragma unroll
    for (int i = 0; i < 4; ++i) if (i < w) bq += wcq[i];
    int oq = bq + pq - cq;
#pragma unroll
    for (int r = 0; r < 8; ++r)
        if (qv[r]) {
            q2b[oq] = fmaf(qx[r], qx[r], fmaf(qy[r], qy[r], qz[r] * qz[r]));
            ++oq;
        }
    if (tid == BLK - 1) nd_s = bq + pq;
    __syncthreads();
    const int nd = nd_s;

    const float* pr = part + (size_t)grp * NSL * RAWC;
    float s = 0.f, c = 0.f;
#pragma unroll
    for (int k = 0; k < 8; ++k) {
        const int q = k * BLK + tid;
        if (q < nd) {
            float m = -1e30f;
#pragma unroll
            for (int s2 = 0; s2 < NSL; ++s2)
                m = fmaxf(m, pr[(size_t)s2 * RAWC + q]);   // coalesced
            const float dd = fmaxf(q2b[q] - m, 0.f);
            if (dd < THR) { s += dd; c += 1.f; }
        }
    }
#pragma unroll
    for (int off = 32; off; off >>= 1) {
        s += __shfl_down(s, off);
        c += __shfl_down(c, off);
    }
    if (lane == 0) { red[w] = s; red[4 + w] = c; }
    __syncthreads();
    if (tid == 0) {
        float* psum  = (float*)(ctl + 1056);
        float* pcnt  = (float*)(ctl + 1088);
        float* meanv = (float*)(ctl + 288);
        psum[grp] = red[0] + red[1] + red[2] + red[3];
        pcnt[grp] = red[4] + red[5] + red[6] + red[7];
        const unsigned r1 = __hip_atomic_fetch_add(&ctl[qi * 32], 1u,
                               __ATOMIC_ACQ_REL, __HIP_MEMORY_SCOPE_AGENT);
        if (r1 == NQC - 1) {               // last chunk of this qi
            float S = 0.f, C = 0.f;
#pragma unroll
            for (int g = 0; g < NQC; ++g) {
                S += psum[qi * NQC + g];
                C += pcnt[qi * NQC + g];
            }
            meanv[qi] = S / C;
            const unsigned r2 = __hip_atomic_fetch_add(&ctl[256], 1u,
                                   __ATOMIC_ACQ_REL, __HIP_MEMORY_SCOPE_AGENT);
            if (r2 == NQI - 1) {           // very last qi
                float a = 0.f;
#pragma unroll
                for (int i = 0; i < NQI; ++i) a += meanv[i];
                out[0] = a;
            }
        }
    }
}

extern "C" void kernel_launch(void* const* d_in, const int* in_sizes, int n_in,
                              void* d_out, int out_size, void* d_ws, size_t ws_size,
                              hipStream_t stream)
{
    const float* Ps = (const float*)d_in[0];   // points_src  [B,N,3]
    const float* Pd = (const float*)d_in[1];   // points_dst  [B,N,3]
    const float* F  = (const float*)d_in[2];   // flows_pred  [B,N,3]
    // d_in[3] = flows_gt (unused by reference)
    const int* Ms = (const int*)d_in[4];       // masks_src [B,N]
    const int* Md = (const int*)d_in[5];       // masks_dst [B,N]
    float* out = (float*)d_out;

    unsigned* ctl = (unsigned*)d_ws;
    float* part = (float*)((char*)d_ws + OFF_PART);

    knn_kernel<<<dim3(NQC * NSL, 2, NB), BLK, 0, stream>>>(
        Ps, Pd, F, Ms, Md, part, ctl);

    final_kernel<<<dim3(NQC, 2, NB), BLK, 0, stream>>>(
        Ps, Pd, F, Ms, Md, part, ctl, out);
}